// Round 3
// baseline (1889.938 us; speedup 1.0000x reference)
//
#include <hip/hip_runtime.h>

typedef unsigned short u16;
typedef __attribute__((ext_vector_type(8))) short bfx8;   // 8 bf16 in 4 VGPRs
typedef __attribute__((ext_vector_type(4))) float f32x4;
typedef __attribute__((ext_vector_type(4))) unsigned short u16x4;

__device__ __forceinline__ float bf2f(u16 u){ return __builtin_bit_cast(float, (unsigned)u << 16); }
__device__ __forceinline__ u16 f2bf(float f){
  unsigned u = __builtin_bit_cast(unsigned, f);
  return (u16)((u + 0x7fffu + ((u >> 16) & 1u)) >> 16);
}

__device__ __forceinline__ void gload_lds16(const void* g, void* l){
  __builtin_amdgcn_global_load_lds((const __attribute__((address_space(1))) void*)g,
                                   (__attribute__((address_space(3))) void*)l, 16, 0, 0);
}

// ---------------- fp32 -> bf16 convert ----------------
__global__ __launch_bounds__(256) void cvt_kernel(const float* __restrict__ in, u16* __restrict__ out, int n4){
  int i = blockIdx.x * 256 + threadIdx.x;
  if (i >= n4) return;
  f32x4 v = *(const f32x4*)&in[(long)i * 4];
  u16x4 o = { f2bf(v[0]), f2bf(v[1]), f2bf(v[2]), f2bf(v[3]) };
  *(u16x4*)&out[(long)i * 4] = o;
}

// ---------------- GEMM: C = A[M,K](bf16,rm) @ W[N,K](bf16,rm)^T ----------------
// grid = (M/128, N/128); column blocks [0,nsplit) -> out0/ld0, rest -> out1/ld1
template<int F32OUT>
__global__ __launch_bounds__(256)
void gemm_bt(const u16* __restrict__ A, const u16* __restrict__ W,
             void* __restrict__ out0, void* __restrict__ out1,
             int K, int ld0, int ld1, int nsplit)
{
  __shared__ __align__(16) u16 At[2][128 * 32];
  __shared__ __align__(16) u16 Bt[2][128 * 32];
  const int tid = threadIdx.x;
  const int bm = blockIdx.x, bn = blockIdx.y;
  const int wid = tid >> 6, lane = tid & 63;
  const int wm = (wid >> 1) << 6, wn = (wid & 1) << 6;
  const u16* ga = A + (long)(bm * 128 + (tid >> 2)) * K + (tid & 3) * 8;
  const u16* gb = W + (long)(bn * 128 + (tid >> 2)) * K + (tid & 3) * 8;
  const int ldso = (tid >> 2) * 32 + (tid & 3) * 8;
  const long gstep = (long)64 * K;

  f32x4 acc[4][4] = {};

  gload_lds16(ga, &At[0][ldso]);
  gload_lds16(ga + gstep, &At[0][2048 + ldso]);
  gload_lds16(gb, &Bt[0][ldso]);
  gload_lds16(gb + gstep, &Bt[0][2048 + ldso]);
  __syncthreads();

  const int nk = K >> 5;
  const int rr = lane & 15, ko = (lane >> 4) << 3;
  for (int kt = 0; kt < nk; ++kt){
    const int cur = kt & 1;
    if (kt + 1 < nk){
      const u16* a2 = ga + (long)(kt + 1) * 32;
      const u16* b2 = gb + (long)(kt + 1) * 32;
      gload_lds16(a2, &At[cur ^ 1][ldso]);
      gload_lds16(a2 + gstep, &At[cur ^ 1][2048 + ldso]);
      gload_lds16(b2, &Bt[cur ^ 1][ldso]);
      gload_lds16(b2 + gstep, &Bt[cur ^ 1][2048 + ldso]);
    }
    bfx8 af[4], bf[4];
#pragma unroll
    for (int mt = 0; mt < 4; mt++) af[mt] = *(const bfx8*)&At[cur][(wm + mt * 16 + rr) * 32 + ko];
#pragma unroll
    for (int nt = 0; nt < 4; nt++) bf[nt] = *(const bfx8*)&Bt[cur][(wn + nt * 16 + rr) * 32 + ko];
#pragma unroll
    for (int mt = 0; mt < 4; mt++)
#pragma unroll
      for (int nt = 0; nt < 4; nt++)
        acc[mt][nt] = __builtin_amdgcn_mfma_f32_16x16x32_bf16(af[mt], bf[nt], acc[mt][nt], 0, 0, 0);
    __syncthreads();
  }

  int bn2 = bn; void* op = out0; int ldo = ld0;
  if (bn >= nsplit){ bn2 = bn - nsplit; op = out1; ldo = ld1; }
  const int row0 = bm * 128 + wm + (lane >> 4) * 4;
  const int col0 = bn2 * 128 + wn + rr;
#pragma unroll
  for (int mt = 0; mt < 4; mt++)
#pragma unroll
    for (int nt = 0; nt < 4; nt++)
#pragma unroll
      for (int r4 = 0; r4 < 4; r4++){
        long idx = (long)(row0 + mt * 16 + r4) * ldo + col0 + nt * 16;
        if (F32OUT) ((float*)op)[idx] = acc[mt][nt][r4];
        else        ((u16*)op)[idx]  = f2bf(acc[mt][nt][r4]);
      }
}

// ---------------- dt: fp32 dot (64 cols) + softplus + clip ----------------
__global__ __launch_bounds__(256) void dt_kernel(const float* __restrict__ hs, const float* __restrict__ w,
                                                 const float* __restrict__ dt_bias, float* __restrict__ dtp){
  int r = threadIdx.x >> 6, j = threadIdx.x & 63;
  long row = (long)blockIdx.x * 4 + r;
  const float* a  = hs + row * 2048;
  const float* wr = w + (long)(8448 + j) * 2048;
  float acc = 0.f;
  for (int k = 0; k < 2048; k += 4){
    f32x4 av = *(const f32x4*)&a[k];
    f32x4 wv = *(const f32x4*)&wr[k];
#pragma unroll
    for (int t = 0; t < 4; t++) acc += av[t] * wv[t];
  }
  float x = acc + dt_bias[j];
  float sp = (x > 20.f) ? x : log1pf(expf(x));
  sp = fminf(fmaxf(sp, 0.f), 100.f);
  dtp[row * 64 + j] = sp;
}

// ---------------- per (b,h,chunk): Adt cumsum (fp32) ----------------
__global__ __launch_bounds__(64) void acum_kernel(const float* __restrict__ dtp, const float* __restrict__ A_log,
                                                  float* __restrict__ acum, float* __restrict__ suma){
  int bid = blockIdx.x;                 // ((b*64+h)*16+c)
  int c = bid & 15, h = (bid >> 4) & 63, b = bid >> 10;
  int lane = threadIdx.x;
  float Ah = -expf(A_log[h]);
  long base = ((long)(b * 4096 + c * 256)) * 64 + h;
  float v[4]; float s = 0.f;
#pragma unroll
  for (int i = 0; i < 4; i++){ float adt = dtp[base + (lane * 4 + i) * 64] * Ah; s += adt; v[i] = s; }
  float tot = s, run = s;
  for (int off = 1; off < 64; off <<= 1){ float u = __shfl_up(run, off); if (lane >= off) run += u; }
  float excl = run - tot;
  long ob = (long)bid * 256 + lane * 4;
#pragma unroll
  for (int i = 0; i < 4; i++) acum[ob + i] = excl + v[i];
  if (lane == 63) suma[bid] = run;
}

// ---------------- depthwise conv + bias + silu + split ----------------
__global__ __launch_bounds__(256) void conv_kernel(const u16* __restrict__ xbc, const float* __restrict__ cw,
                                                   const float* __restrict__ cb,
                                                   u16* __restrict__ xact,
                                                   u16* __restrict__ bmat, u16* __restrict__ cmat){
  int pos = blockIdx.x;                 // b*4096 + l
  int l = pos & 4095;
  for (int ch = threadIdx.x; ch < 4352; ch += 256){
    float acc = cb[ch];
#pragma unroll
    for (int k = 0; k < 4; k++){
      int lp = l + k - 3;
      if (lp >= 0) acc += cw[ch * 4 + k] * bf2f(xbc[(long)(pos + k - 3) * 4352 + ch]);
    }
    float val = acc / (1.f + expf(-acc));
    if (ch < 4096)      xact[(long)pos * 4096 + ch] = f2bf(val);
    else if (ch < 4224) bmat[(long)pos * 128 + ch - 4096] = f2bf(val);
    else                cmat[(long)pos * 128 + ch - 4224] = f2bf(val);
  }
}

// ---------------- per (b,c,h): chunk end-state E = (X*dt*decay)^T @ B  (bf16 out) ----------------
__global__ __launch_bounds__(256) void states_kernel(const u16* __restrict__ xact, const u16* __restrict__ bmat,
                                                     const float* __restrict__ acum, const float* __restrict__ suma,
                                                     const float* __restrict__ dtp, u16* __restrict__ stR){
  __shared__ __align__(16) u16 XdT[64 * 264];
  __shared__ __align__(16) u16 BT[128 * 264];
  __shared__ float fac[256];
  int bid = blockIdx.x;                 // ((b*16+c)*64+h)
  int h = bid & 63, c = (bid >> 6) & 15, b = bid >> 10;
  int tid = threadIdx.x;
  long rowbase = (long)b * 4096 + c * 256;
  long aco = ((long)((b * 64 + h) * 16 + c)) * 256;
  float sA = suma[(b * 64 + h) * 16 + c];
  fac[tid] = dtp[(rowbase + tid) * 64 + h] * expf(sA - acum[aco + tid]);
  __syncthreads();
  for (int idx = tid; idx < 16384; idx += 256){
    int l = idx >> 6, p = idx & 63;
    XdT[p * 264 + l] = f2bf(bf2f(xact[(rowbase + l) * 4096 + h * 64 + p]) * fac[l]);
  }
  for (int idx = tid; idx < 32768; idx += 256){
    int l = idx >> 7, n = idx & 127;
    BT[n * 264 + l] = bmat[(rowbase + l) * 128 + n];
  }
  __syncthreads();
  int wid = tid >> 6, lane = tid & 63;
  int rr = lane & 15, ko = (lane >> 4) * 8;
  f32x4 acc[8] = {};
#pragma unroll
  for (int ks = 0; ks < 8; ks++){
    bfx8 a = *(const bfx8*)&XdT[(wid * 16 + rr) * 264 + ks * 32 + ko];
#pragma unroll
    for (int nt = 0; nt < 8; nt++){
      bfx8 bb = *(const bfx8*)&BT[(nt * 16 + rr) * 264 + ks * 32 + ko];
      acc[nt] = __builtin_amdgcn_mfma_f32_16x16x32_bf16(a, bb, acc[nt], 0, 0, 0);
    }
  }
  long ob = (long)bid * 8192;
#pragma unroll
  for (int nt = 0; nt < 8; nt++)
#pragma unroll
    for (int r4 = 0; r4 < 4; r4++){
      int p = wid * 16 + (lane >> 4) * 4 + r4;
      stR[ob + p * 128 + nt * 16 + rr] = f2bf(acc[nt][r4]);
    }
}

// ---------------- inter-chunk scan: in-place E -> R (prev_states), bf16 ----------------
__global__ __launch_bounds__(256) void scan_kernel(u16* stR, const float* __restrict__ suma){
  int bh = blockIdx.x; int b = bh >> 6, h = bh & 63;
  int tid = threadIdx.x;
  f32x4 R[8] = {};
  for (int c = 0; c < 16; c++){
    long base = ((long)((b * 16 + c) * 64 + h)) * 8192;
    float sc = expf(suma[(b * 64 + h) * 16 + c]);
#pragma unroll
    for (int i = 0; i < 8; i++){
      long off = base + i * 1024 + tid * 4;
      u16x4 e4 = *(const u16x4*)&stR[off];
      u16x4 o = { f2bf(R[i][0]), f2bf(R[i][1]), f2bf(R[i][2]), f2bf(R[i][3]) };
      *(u16x4*)&stR[off] = o;
#pragma unroll
      for (int t = 0; t < 4; t++) R[i][t] = sc * R[i][t] + bf2f(e4[t]);
    }
  }
}

// ---------------- per (b,c,h): Y = (CB^T ∘ L) @ Xdt + exp(Acum)*(C @ R^T) + x*D ----------------
// NOTE: ybuf may alias xact (in-place): block-owned region, reads precede writes across barrier.
__global__ __launch_bounds__(256) void ydiag_kernel(const u16* __restrict__ cmat, const u16* __restrict__ bmat,
                                                    const u16* xact,
                                                    const u16* __restrict__ rbuf, const float* __restrict__ acum,
                                                    const float* __restrict__ dtp,
                                                    const float* __restrict__ Dv, u16* ybuf){
  __shared__ __align__(16) u16 Ct[256 * 136];
  __shared__ __align__(16) u16 Bth[128 * 136];
  __shared__ __align__(16) u16 XdT[64 * 264];
  __shared__ __align__(16) u16 Sb[4][64 * 40];
  __shared__ float acL[256];
  __shared__ float dtl[256];
  int bid = blockIdx.x;                 // ((b*16+c)*64+h)
  int h = bid & 63, c = (bid >> 6) & 15, b = bid >> 10;
  int tid = threadIdx.x, wid = tid >> 6, lane = tid & 63;
  long rowbase = (long)b * 4096 + c * 256;
  long aco = ((long)((b * 64 + h) * 16 + c)) * 256;
  acL[tid] = acum[aco + tid];
  dtl[tid] = dtp[(rowbase + tid) * 64 + h];
  __syncthreads();
  for (int v = tid; v < 4096; v += 256){
    int l = v >> 4, no = (v & 15) * 8;
    *(bfx8*)&Ct[l * 136 + no] = *(const bfx8*)&cmat[(rowbase + l) * 128 + no];
  }
  for (int idx = tid; idx < 16384; idx += 256){
    int l = idx >> 6, p = idx & 63;
    XdT[p * 264 + l] = f2bf(bf2f(xact[(rowbase + l) * 4096 + h * 64 + p]) * dtl[l]);
  }
  for (int v = tid; v < 2048; v += 256){
    int s = v >> 4, no = (v & 15) * 8;
    *(bfx8*)&Bth[s * 136 + no] = *(const bfx8*)&bmat[(rowbase + s) * 128 + no];
  }
  __syncthreads();

  int rr = lane & 15, ko = (lane >> 4) * 8;
  f32x4 acc[4][4] = {};

  // Y_off = C @ R^T, scaled by exp(acum[l])
  long rb = (long)bid * 8192;
#pragma unroll
  for (int kk = 0; kk < 4; kk++){
    bfx8 a[4];
#pragma unroll
    for (int lt = 0; lt < 4; lt++) a[lt] = *(const bfx8*)&Ct[(wid * 64 + lt * 16 + rr) * 136 + kk * 32 + ko];
#pragma unroll
    for (int pt = 0; pt < 4; pt++){
      bfx8 bb = *(const bfx8*)&rbuf[rb + (pt * 16 + rr) * 128 + kk * 32 + ko];
#pragma unroll
      for (int lt = 0; lt < 4; lt++) acc[lt][pt] = __builtin_amdgcn_mfma_f32_16x16x32_bf16(a[lt], bb, acc[lt][pt], 0, 0, 0);
    }
  }
#pragma unroll
  for (int lt = 0; lt < 4; lt++)
#pragma unroll
    for (int r4 = 0; r4 < 4; r4++){
      float e = expf(acL[wid * 64 + lt * 16 + (lane >> 4) * 4 + r4]);
#pragma unroll
      for (int pt = 0; pt < 4; pt++) acc[lt][pt][r4] *= e;
    }

  int nsp = 2 * (wid + 1);   // causal: wave w needs s-pairs 0..2w+1
  for (int half = 0; half < 2; half++){
    if (half == 1){
      __syncthreads();
      for (int v = tid; v < 2048; v += 256){
        int s = v >> 4, no = (v & 15) * 8;
        *(bfx8*)&Bth[s * 136 + no] = *(const bfx8*)&bmat[(rowbase + 128 + s) * 128 + no];
      }
      __syncthreads();
    }
    int sp0 = half * 4;
    int sp1 = nsp < sp0 + 4 ? nsp : sp0 + 4;
    for (int sp = sp0; sp < sp1; sp++){
      int s0 = sp * 32, srow = s0 & 127;
      f32x4 sacc[2][4] = {};
#pragma unroll
      for (int kk = 0; kk < 4; kk++){
        bfx8 a[4];
#pragma unroll
        for (int lt = 0; lt < 4; lt++) a[lt] = *(const bfx8*)&Ct[(wid * 64 + lt * 16 + rr) * 136 + kk * 32 + ko];
#pragma unroll
        for (int st = 0; st < 2; st++){
          bfx8 bb = *(const bfx8*)&Bth[(srow + st * 16 + rr) * 136 + kk * 32 + ko];
#pragma unroll
          for (int lt = 0; lt < 4; lt++) sacc[st][lt] = __builtin_amdgcn_mfma_f32_16x16x32_bf16(a[lt], bb, sacc[st][lt], 0, 0, 0);
        }
      }
#pragma unroll
      for (int st = 0; st < 2; st++)
#pragma unroll
        for (int lt = 0; lt < 4; lt++)
#pragma unroll
          for (int r4 = 0; r4 < 4; r4++){
            int lrow = wid * 64 + lt * 16 + (lane >> 4) * 4 + r4;
            int scol = s0 + st * 16 + rr;
            float vv = (scol <= lrow) ? sacc[st][lt][r4] * expf(acL[lrow] - acL[scol]) : 0.f;
            Sb[wid][(lt * 16 + (lane >> 4) * 4 + r4) * 40 + st * 16 + rr] = f2bf(vv);
          }
      asm volatile("s_waitcnt lgkmcnt(0)" ::: "memory");
      __builtin_amdgcn_sched_barrier(0);
#pragma unroll
      for (int lt = 0; lt < 4; lt++){
        bfx8 a1 = *(const bfx8*)&Sb[wid][(lt * 16 + rr) * 40 + ko];
#pragma unroll
        for (int pt = 0; pt < 4; pt++){
          bfx8 bb = *(const bfx8*)&XdT[(pt * 16 + rr) * 264 + s0 + ko];
          acc[lt][pt] = __builtin_amdgcn_mfma_f32_16x16x32_bf16(a1, bb, acc[lt][pt], 0, 0, 0);
        }
      }
    }
  }
  float Dh = Dv[h];
#pragma unroll
  for (int lt = 0; lt < 4; lt++)
#pragma unroll
    for (int pt = 0; pt < 4; pt++)
#pragma unroll
      for (int r4 = 0; r4 < 4; r4++){
        int lrow = wid * 64 + lt * 16 + (lane >> 4) * 4 + r4;
        int pcol = pt * 16 + rr;
        long gi = (rowbase + lrow) * 4096 + h * 64 + pcol;
        ybuf[gi] = f2bf(acc[lt][pt][r4] + bf2f(xact[gi]) * Dh);
      }
}

// ---------------- RMSNorm + silu(z) gate (may write in place over ybuf) ----------------
__global__ __launch_bounds__(256) void rms_kernel(const u16* ybuf, const u16* zbuf,
                                                  const float* __restrict__ norm_w, u16* ynorm){
  __shared__ float red[4];
  long row = blockIdx.x;
  int tid = threadIdx.x;
  long yb = row * 4096 + tid * 16;
  bfx8 v0 = *(const bfx8*)&ybuf[yb];
  bfx8 v1 = *(const bfx8*)&ybuf[yb + 8];
  float vals[16];
#pragma unroll
  for (int t = 0; t < 8; t++){ vals[t] = bf2f((u16)v0[t]); vals[8 + t] = bf2f((u16)v1[t]); }
  float ss = 0.f;
#pragma unroll
  for (int t = 0; t < 16; t++) ss += vals[t] * vals[t];
#pragma unroll
  for (int off = 32; off >= 1; off >>= 1) ss += __shfl_xor(ss, off);
  if ((tid & 63) == 0) red[tid >> 6] = ss;
  __syncthreads();
  float rs = rsqrtf((red[0] + red[1] + red[2] + red[3]) * (1.f / 4096.f) + 1e-5f);
  bfx8 z0 = *(const bfx8*)&zbuf[yb];
  bfx8 z1 = *(const bfx8*)&zbuf[yb + 8];
  bfx8 o0, o1;
#pragma unroll
  for (int t = 0; t < 16; t++){
    float zv = bf2f((u16)(t < 8 ? z0[t] : z1[t - 8]));
    float g = zv / (1.f + expf(-zv));
    u16 r = f2bf(vals[t] * rs * norm_w[tid * 16 + t] * g);
    if (t < 8) o0[t] = (short)r; else o1[t - 8] = (short)r;
  }
  *(bfx8*)&ynorm[yb] = o0;
  *(bfx8*)&ynorm[yb + 8] = o1;
}

extern "C" void kernel_launch(void* const* d_in, const int* in_sizes, int n_in,
                              void* d_out, int out_size, void* d_ws, size_t ws_size,
                              hipStream_t stream){
  const float* hs   = (const float*)d_in[0];
  const float* inw  = (const float*)d_in[1];
  const float* cw   = (const float*)d_in[2];
  const float* cb   = (const float*)d_in[3];
  const float* dtb  = (const float*)d_in[4];
  const float* alog = (const float*)d_in[5];
  const float* Dv   = (const float*)d_in[6];
  const float* nw   = (const float*)d_in[7];
  const float* outw = (const float*)d_in[8];

  // Workspace layout: 147,857,408 B required. z lives in d_out (exactly 64 MiB).
  const size_t REQ = 147857408ULL;
  if (ws_size < REQ){
    // diagnostic signature: absmax ~48 => ws still too small
    hipMemsetAsync(d_out, 0x42, (size_t)out_size * 4, stream);
    return;
  }
  char* ws = (char*)d_ws;
  u16*   hsb  = (u16*)  (ws + 0L);             // 33,554,432   (dead after gemm1)
  u16*   wbi  = (u16*)  (ws + 33554432L);      // 34,603,008   (dead after gemm1)
  u16*   xbc  = (u16*)  (ws + 68157440L);      // 71,303,168   (dead after conv)
  u16*   xact = (u16*)  (ws + 0L);             // 67,108,864   (overlays hsb+wbi; = ybuf = ynorm)
  u16*   stR  = (u16*)  (ws + 68157440L);      // 33,554,432   (overlays xbc)
  u16*   wbo  = (u16*)  (ws + 101711872L);     // 16,777,216   (overlays xbc tail)
  float* dtp  = (float*)(ws + 139460608L);     //  2,097,152
  float* acum = (float*)(ws + 141557760L);     //  2,097,152
  float* suma = (float*)(ws + 143654912L);     //      8,192
  u16*   bmat = (u16*)  (ws + 143663104L);     //  2,097,152
  u16*   cmat = (u16*)  (ws + 145760256L);     //  2,097,152  (end = 147,857,408)
  u16*   zbuf = (u16*)  d_out;                 // 67,108,864 = exactly out_size*4

  cvt_kernel<<<16384, 256, 0, stream>>>(hs, hsb, 4194304);
  cvt_kernel<<<16896, 256, 0, stream>>>(inw, wbi, 4325376);
  gemm_bt<0><<<dim3(64, 66), 256, 0, stream>>>(hsb, wbi, zbuf, xbc, 2048, 4096, 4352, 32);
  dt_kernel<<<2048, 256, 0, stream>>>(hs, inw, dtb, dtp);
  acum_kernel<<<2048, 64, 0, stream>>>(dtp, alog, acum, suma);
  conv_kernel<<<8192, 256, 0, stream>>>(xbc, cw, cb, xact, bmat, cmat);    // xact over dead hsb+wbi
  cvt_kernel<<<8192, 256, 0, stream>>>(outw, wbo, 2097152);                // wbo over dead xbc tail
  states_kernel<<<2048, 256, 0, stream>>>(xact, bmat, acum, suma, dtp, stR);
  scan_kernel<<<128, 256, 0, stream>>>(stR, suma);
  ydiag_kernel<<<2048, 256, 0, stream>>>(cmat, bmat, xact, stR, acum, dtp, Dv, xact);  // in-place Y
  rms_kernel<<<8192, 256, 0, stream>>>(xact, zbuf, nw, xact);                           // in-place norm
  gemm_bt<1><<<dim3(64, 16), 256, 0, stream>>>(xact, wbo, d_out, d_out, 4096, 2048, 2048, 999);
}

// Round 4
// 1400.082 us; speedup vs baseline: 1.3499x; 1.3499x over previous
//
#include <hip/hip_runtime.h>

typedef unsigned short u16;
typedef __attribute__((ext_vector_type(8))) short bfx8;   // 8 bf16 in 4 VGPRs
typedef __attribute__((ext_vector_type(4))) float f32x4;
typedef __attribute__((ext_vector_type(4))) unsigned short u16x4;

__device__ __forceinline__ float bf2f(u16 u){ return __builtin_bit_cast(float, (unsigned)u << 16); }
__device__ __forceinline__ u16 f2bf(float f){
  unsigned u = __builtin_bit_cast(unsigned, f);
  return (u16)((u + 0x7fffu + ((u >> 16) & 1u)) >> 16);
}

__device__ __forceinline__ void gload_lds16(const void* g, void* l){
  __builtin_amdgcn_global_load_lds((const __attribute__((address_space(1))) void*)g,
                                   (__attribute__((address_space(3))) void*)l, 16, 0, 0);
}

// ---------------- fp32 -> bf16 convert ----------------
__global__ __launch_bounds__(256) void cvt_kernel(const float* __restrict__ in, u16* __restrict__ out, int n4){
  int i = blockIdx.x * 256 + threadIdx.x;
  if (i >= n4) return;
  f32x4 v = *(const f32x4*)&in[(long)i * 4];
  u16x4 o = { f2bf(v[0]), f2bf(v[1]), f2bf(v[2]), f2bf(v[3]) };
  *(u16x4*)&out[(long)i * 4] = o;
}

// ---------------- GEMM: C = A[M,K](bf16,rm) @ W[N,K](bf16,rm)^T ----------------
// grid = (M/128, N/128); column blocks [0,nsplit) -> out0/ld0, rest -> out1/ld1
template<int F32OUT>
__global__ __launch_bounds__(256)
void gemm_bt(const u16* __restrict__ A, const u16* __restrict__ W,
             void* __restrict__ out0, void* __restrict__ out1,
             int K, int ld0, int ld1, int nsplit)
{
  __shared__ __align__(16) u16 At[2][128 * 32];
  __shared__ __align__(16) u16 Bt[2][128 * 32];
  const int tid = threadIdx.x;
  const int bm = blockIdx.x, bn = blockIdx.y;
  const int wid = tid >> 6, lane = tid & 63;
  const int wm = (wid >> 1) << 6, wn = (wid & 1) << 6;
  const u16* ga = A + (long)(bm * 128 + (tid >> 2)) * K + (tid & 3) * 8;
  const u16* gb = W + (long)(bn * 128 + (tid >> 2)) * K + (tid & 3) * 8;
  const int ldso = (tid >> 2) * 32 + (tid & 3) * 8;
  const long gstep = (long)64 * K;

  f32x4 acc[4][4] = {};

  gload_lds16(ga, &At[0][ldso]);
  gload_lds16(ga + gstep, &At[0][2048 + ldso]);
  gload_lds16(gb, &Bt[0][ldso]);
  gload_lds16(gb + gstep, &Bt[0][2048 + ldso]);
  __syncthreads();

  const int nk = K >> 5;
  const int rr = lane & 15, ko = (lane >> 4) << 3;
  for (int kt = 0; kt < nk; ++kt){
    const int cur = kt & 1;
    if (kt + 1 < nk){
      const u16* a2 = ga + (long)(kt + 1) * 32;
      const u16* b2 = gb + (long)(kt + 1) * 32;
      gload_lds16(a2, &At[cur ^ 1][ldso]);
      gload_lds16(a2 + gstep, &At[cur ^ 1][2048 + ldso]);
      gload_lds16(b2, &Bt[cur ^ 1][ldso]);
      gload_lds16(b2 + gstep, &Bt[cur ^ 1][2048 + ldso]);
    }
    bfx8 af[4], bf[4];
#pragma unroll
    for (int mt = 0; mt < 4; mt++) af[mt] = *(const bfx8*)&At[cur][(wm + mt * 16 + rr) * 32 + ko];
#pragma unroll
    for (int nt = 0; nt < 4; nt++) bf[nt] = *(const bfx8*)&Bt[cur][(wn + nt * 16 + rr) * 32 + ko];
#pragma unroll
    for (int mt = 0; mt < 4; mt++)
#pragma unroll
      for (int nt = 0; nt < 4; nt++)
        acc[mt][nt] = __builtin_amdgcn_mfma_f32_16x16x32_bf16(af[mt], bf[nt], acc[mt][nt], 0, 0, 0);
    __syncthreads();
  }

  int bn2 = bn; void* op = out0; int ldo = ld0;
  if (bn >= nsplit){ bn2 = bn - nsplit; op = out1; ldo = ld1; }
  const int row0 = bm * 128 + wm + (lane >> 4) * 4;
  const int col0 = bn2 * 128 + wn + rr;
#pragma unroll
  for (int mt = 0; mt < 4; mt++)
#pragma unroll
    for (int nt = 0; nt < 4; nt++)
#pragma unroll
      for (int r4 = 0; r4 < 4; r4++){
        long idx = (long)(row0 + mt * 16 + r4) * ldo + col0 + nt * 16;
        if (F32OUT) ((float*)op)[idx] = acc[mt][nt][r4];
        else        ((u16*)op)[idx]  = f2bf(acc[mt][nt][r4]);
      }
}

// ---------------- dt: LDS-tiled fp32 skinny GEMM (8192x64, K=2048) + softplus + clip ----------------
// 256 blocks x (32 rows x 64 cols); thread = (rgrp, j); 8 f32x4 accumulators
__global__ __launch_bounds__(256) void dt_kernel(const float* __restrict__ hs, const float* __restrict__ w,
                                                 const float* __restrict__ dt_bias, float* __restrict__ dtp){
  __shared__ float hsS[32][66];
  __shared__ float wS[64][66];
  const int tid = threadIdx.x;
  const int j = tid & 63, rgrp = tid >> 6;
  const long row0 = (long)blockIdx.x * 32;
  const int srow = tid >> 3, sc0 = (tid & 7) * 8;     // hs staging: 32 rows x 64
  const int wrow = tid >> 2, wc0 = (tid & 3) * 16;    // w staging: 64 rows x 64
  const float* hsg = hs + (row0 + srow) * 2048 + sc0;
  const float* wg  = w + (long)(8448 + wrow) * 2048 + wc0;

  f32x4 acc[8] = {};
  for (int k0 = 0; k0 < 2048; k0 += 64){
    *(f32x4*)&hsS[srow][sc0]     = *(const f32x4*)&hsg[k0];
    *(f32x4*)&hsS[srow][sc0 + 4] = *(const f32x4*)&hsg[k0 + 4];
#pragma unroll
    for (int q = 0; q < 4; q++)
      *(f32x4*)&wS[wrow][wc0 + q * 4] = *(const f32x4*)&wg[k0 + q * 4];
    __syncthreads();
#pragma unroll
    for (int kk = 0; kk < 64; kk += 4){
      f32x4 wv = *(const f32x4*)&wS[j][kk];
#pragma unroll
      for (int r = 0; r < 8; r++){
        f32x4 hv = *(const f32x4*)&hsS[rgrp * 8 + r][kk];
        acc[r] += hv * wv;
      }
    }
    __syncthreads();
  }
  float bias = dt_bias[j];
#pragma unroll
  for (int r = 0; r < 8; r++){
    float x = acc[r][0] + acc[r][1] + acc[r][2] + acc[r][3] + bias;
    float sp = (x > 20.f) ? x : log1pf(expf(x));
    sp = fminf(fmaxf(sp, 0.f), 100.f);
    dtp[(row0 + rgrp * 8 + r) * 64 + j] = sp;
  }
}

// ---------------- per (b,h,chunk): Adt cumsum (fp32) ----------------
__global__ __launch_bounds__(64) void acum_kernel(const float* __restrict__ dtp, const float* __restrict__ A_log,
                                                  float* __restrict__ acum, float* __restrict__ suma){
  int bid = blockIdx.x;                 // ((b*64+h)*16+c)
  int c = bid & 15, h = (bid >> 4) & 63, b = bid >> 10;
  int lane = threadIdx.x;
  float Ah = -expf(A_log[h]);
  long base = ((long)(b * 4096 + c * 256)) * 64 + h;
  float v[4]; float s = 0.f;
#pragma unroll
  for (int i = 0; i < 4; i++){ float adt = dtp[base + (lane * 4 + i) * 64] * Ah; s += adt; v[i] = s; }
  float tot = s, run = s;
  for (int off = 1; off < 64; off <<= 1){ float u = __shfl_up(run, off); if (lane >= off) run += u; }
  float excl = run - tot;
  long ob = (long)bid * 256 + lane * 4;
#pragma unroll
  for (int i = 0; i < 4; i++) acum[ob + i] = excl + v[i];
  if (lane == 63) suma[bid] = run;
}

// ---------------- depthwise conv + bias + silu + split ----------------
__global__ __launch_bounds__(256) void conv_kernel(const u16* __restrict__ xbc, const float* __restrict__ cw,
                                                   const float* __restrict__ cb,
                                                   u16* __restrict__ xact,
                                                   u16* __restrict__ bmat, u16* __restrict__ cmat){
  int pos = blockIdx.x;                 // b*4096 + l
  int l = pos & 4095;
  for (int ch = threadIdx.x; ch < 4352; ch += 256){
    float acc = cb[ch];
#pragma unroll
    for (int k = 0; k < 4; k++){
      int lp = l + k - 3;
      if (lp >= 0) acc += cw[ch * 4 + k] * bf2f(xbc[(long)(pos + k - 3) * 4352 + ch]);
    }
    float val = acc / (1.f + expf(-acc));
    if (ch < 4096)      xact[(long)pos * 4096 + ch] = f2bf(val);
    else if (ch < 4224) bmat[(long)pos * 128 + ch - 4096] = f2bf(val);
    else                cmat[(long)pos * 128 + ch - 4224] = f2bf(val);
  }
}

// ---------------- per (b,c,h): chunk end-state E = (X*dt*decay)^T @ B  (bf16 out) ----------------
__global__ __launch_bounds__(256) void states_kernel(const u16* __restrict__ xact, const u16* __restrict__ bmat,
                                                     const float* __restrict__ acum, const float* __restrict__ suma,
                                                     const float* __restrict__ dtp, u16* __restrict__ stR){
  __shared__ __align__(16) u16 XdT[64 * 264];
  __shared__ __align__(16) u16 BT[128 * 264];
  __shared__ float fac[256];
  int bid = blockIdx.x;                 // ((b*16+c)*64+h)
  int h = bid & 63, c = (bid >> 6) & 15, b = bid >> 10;
  int tid = threadIdx.x;
  long rowbase = (long)b * 4096 + c * 256;
  long aco = ((long)((b * 64 + h) * 16 + c)) * 256;
  float sA = suma[(b * 64 + h) * 16 + c];
  fac[tid] = dtp[(rowbase + tid) * 64 + h] * expf(sA - acum[aco + tid]);
  __syncthreads();
  for (int idx = tid; idx < 16384; idx += 256){
    int l = idx >> 6, p = idx & 63;
    XdT[p * 264 + l] = f2bf(bf2f(xact[(rowbase + l) * 4096 + h * 64 + p]) * fac[l]);
  }
  for (int idx = tid; idx < 32768; idx += 256){
    int l = idx >> 7, n = idx & 127;
    BT[n * 264 + l] = bmat[(rowbase + l) * 128 + n];
  }
  __syncthreads();
  int wid = tid >> 6, lane = tid & 63;
  int rr = lane & 15, ko = (lane >> 4) * 8;
  f32x4 acc[8] = {};
#pragma unroll
  for (int ks = 0; ks < 8; ks++){
    bfx8 a = *(const bfx8*)&XdT[(wid * 16 + rr) * 264 + ks * 32 + ko];
#pragma unroll
    for (int nt = 0; nt < 8; nt++){
      bfx8 bb = *(const bfx8*)&BT[(nt * 16 + rr) * 264 + ks * 32 + ko];
      acc[nt] = __builtin_amdgcn_mfma_f32_16x16x32_bf16(a, bb, acc[nt], 0, 0, 0);
    }
  }
  long ob = (long)bid * 8192;
#pragma unroll
  for (int nt = 0; nt < 8; nt++)
#pragma unroll
    for (int r4 = 0; r4 < 4; r4++){
      int p = wid * 16 + (lane >> 4) * 4 + r4;
      stR[ob + p * 128 + nt * 16 + rr] = f2bf(acc[nt][r4]);
    }
}

// ---------------- inter-chunk scan: in-place E -> R (prev_states), bf16 ----------------
__global__ __launch_bounds__(256) void scan_kernel(u16* stR, const float* __restrict__ suma){
  int bh = blockIdx.x; int b = bh >> 6, h = bh & 63;
  int tid = threadIdx.x;
  f32x4 R[8] = {};
  for (int c = 0; c < 16; c++){
    long base = ((long)((b * 16 + c) * 64 + h)) * 8192;
    float sc = expf(suma[(b * 64 + h) * 16 + c]);
#pragma unroll
    for (int i = 0; i < 8; i++){
      long off = base + i * 1024 + tid * 4;
      u16x4 e4 = *(const u16x4*)&stR[off];
      u16x4 o = { f2bf(R[i][0]), f2bf(R[i][1]), f2bf(R[i][2]), f2bf(R[i][3]) };
      *(u16x4*)&stR[off] = o;
#pragma unroll
      for (int t = 0; t < 4; t++) R[i][t] = sc * R[i][t] + bf2f(e4[t]);
    }
  }
}

// ---------------- per (b,c,h): Y = (CB^T ∘ L) @ Xdt + exp(Acum)*(C @ R^T) + x*D ----------------
// NOTE: ybuf may alias xact (in-place): block-owned region, reads precede writes across barrier.
__global__ __launch_bounds__(256) void ydiag_kernel(const u16* __restrict__ cmat, const u16* __restrict__ bmat,
                                                    const u16* xact,
                                                    const u16* __restrict__ rbuf, const float* __restrict__ acum,
                                                    const float* __restrict__ dtp,
                                                    const float* __restrict__ Dv, u16* ybuf){
  __shared__ __align__(16) u16 Ct[256 * 136];
  __shared__ __align__(16) u16 Bth[128 * 136];
  __shared__ __align__(16) u16 XdT[64 * 264];
  __shared__ __align__(16) u16 Sb[4][64 * 40];
  __shared__ float acL[256];
  __shared__ float dtl[256];
  int bid = blockIdx.x;                 // ((b*16+c)*64+h)
  int h = bid & 63, c = (bid >> 6) & 15, b = bid >> 10;
  int tid = threadIdx.x, wid = tid >> 6, lane = tid & 63;
  long rowbase = (long)b * 4096 + c * 256;
  long aco = ((long)((b * 64 + h) * 16 + c)) * 256;
  acL[tid] = acum[aco + tid];
  dtl[tid] = dtp[(rowbase + tid) * 64 + h];
  __syncthreads();
  for (int v = tid; v < 4096; v += 256){
    int l = v >> 4, no = (v & 15) * 8;
    *(bfx8*)&Ct[l * 136 + no] = *(const bfx8*)&cmat[(rowbase + l) * 128 + no];
  }
  for (int idx = tid; idx < 16384; idx += 256){
    int l = idx >> 6, p = idx & 63;
    XdT[p * 264 + l] = f2bf(bf2f(xact[(rowbase + l) * 4096 + h * 64 + p]) * dtl[l]);
  }
  for (int v = tid; v < 2048; v += 256){
    int s = v >> 4, no = (v & 15) * 8;
    *(bfx8*)&Bth[s * 136 + no] = *(const bfx8*)&bmat[(rowbase + s) * 128 + no];
  }
  __syncthreads();

  int rr = lane & 15, ko = (lane >> 4) * 8;
  f32x4 acc[4][4] = {};

  // Y_off = C @ R^T, scaled by exp(acum[l])
  long rb = (long)bid * 8192;
#pragma unroll
  for (int kk = 0; kk < 4; kk++){
    bfx8 a[4];
#pragma unroll
    for (int lt = 0; lt < 4; lt++) a[lt] = *(const bfx8*)&Ct[(wid * 64 + lt * 16 + rr) * 136 + kk * 32 + ko];
#pragma unroll
    for (int pt = 0; pt < 4; pt++){
      bfx8 bb = *(const bfx8*)&rbuf[rb + (pt * 16 + rr) * 128 + kk * 32 + ko];
#pragma unroll
      for (int lt = 0; lt < 4; lt++) acc[lt][pt] = __builtin_amdgcn_mfma_f32_16x16x32_bf16(a[lt], bb, acc[lt][pt], 0, 0, 0);
    }
  }
#pragma unroll
  for (int lt = 0; lt < 4; lt++)
#pragma unroll
    for (int r4 = 0; r4 < 4; r4++){
      float e = expf(acL[wid * 64 + lt * 16 + (lane >> 4) * 4 + r4]);
#pragma unroll
      for (int pt = 0; pt < 4; pt++) acc[lt][pt][r4] *= e;
    }

  int nsp = 2 * (wid + 1);   // causal: wave w needs s-pairs 0..2w+1
  for (int half = 0; half < 2; half++){
    if (half == 1){
      __syncthreads();
      for (int v = tid; v < 2048; v += 256){
        int s = v >> 4, no = (v & 15) * 8;
        *(bfx8*)&Bth[s * 136 + no] = *(const bfx8*)&bmat[(rowbase + 128 + s) * 128 + no];
      }
      __syncthreads();
    }
    int sp0 = half * 4;
    int sp1 = nsp < sp0 + 4 ? nsp : sp0 + 4;
    for (int sp = sp0; sp < sp1; sp++){
      int s0 = sp * 32, srow = s0 & 127;
      f32x4 sacc[2][4] = {};
#pragma unroll
      for (int kk = 0; kk < 4; kk++){
        bfx8 a[4];
#pragma unroll
        for (int lt = 0; lt < 4; lt++) a[lt] = *(const bfx8*)&Ct[(wid * 64 + lt * 16 + rr) * 136 + kk * 32 + ko];
#pragma unroll
        for (int st = 0; st < 2; st++){
          bfx8 bb = *(const bfx8*)&Bth[(srow + st * 16 + rr) * 136 + kk * 32 + ko];
#pragma unroll
          for (int lt = 0; lt < 4; lt++) sacc[st][lt] = __builtin_amdgcn_mfma_f32_16x16x32_bf16(a[lt], bb, sacc[st][lt], 0, 0, 0);
        }
      }
#pragma unroll
      for (int st = 0; st < 2; st++)
#pragma unroll
        for (int lt = 0; lt < 4; lt++)
#pragma unroll
          for (int r4 = 0; r4 < 4; r4++){
            int lrow = wid * 64 + lt * 16 + (lane >> 4) * 4 + r4;
            int scol = s0 + st * 16 + rr;
            float vv = (scol <= lrow) ? sacc[st][lt][r4] * expf(acL[lrow] - acL[scol]) : 0.f;
            Sb[wid][(lt * 16 + (lane >> 4) * 4 + r4) * 40 + st * 16 + rr] = f2bf(vv);
          }
      asm volatile("s_waitcnt lgkmcnt(0)" ::: "memory");
      __builtin_amdgcn_sched_barrier(0);
#pragma unroll
      for (int lt = 0; lt < 4; lt++){
        bfx8 a1 = *(const bfx8*)&Sb[wid][(lt * 16 + rr) * 40 + ko];
#pragma unroll
        for (int pt = 0; pt < 4; pt++){
          bfx8 bb = *(const bfx8*)&XdT[(pt * 16 + rr) * 264 + s0 + ko];
          acc[lt][pt] = __builtin_amdgcn_mfma_f32_16x16x32_bf16(a1, bb, acc[lt][pt], 0, 0, 0);
        }
      }
    }
  }
  float Dh = Dv[h];
#pragma unroll
  for (int lt = 0; lt < 4; lt++)
#pragma unroll
    for (int pt = 0; pt < 4; pt++)
#pragma unroll
      for (int r4 = 0; r4 < 4; r4++){
        int lrow = wid * 64 + lt * 16 + (lane >> 4) * 4 + r4;
        int pcol = pt * 16 + rr;
        long gi = (rowbase + lrow) * 4096 + h * 64 + pcol;
        ybuf[gi] = f2bf(acc[lt][pt][r4] + bf2f(xact[gi]) * Dh);
      }
}

// ---------------- RMSNorm + silu(z) gate (may write in place over ybuf) ----------------
__global__ __launch_bounds__(256) void rms_kernel(const u16* ybuf, const u16* zbuf,
                                                  const float* __restrict__ norm_w, u16* ynorm){
  __shared__ float red[4];
  long row = blockIdx.x;
  int tid = threadIdx.x;
  long yb = row * 4096 + tid * 16;
  bfx8 v0 = *(const bfx8*)&ybuf[yb];
  bfx8 v1 = *(const bfx8*)&ybuf[yb + 8];
  float vals[16];
#pragma unroll
  for (int t = 0; t < 8; t++){ vals[t] = bf2f((u16)v0[t]); vals[8 + t] = bf2f((u16)v1[t]); }
  float ss = 0.f;
#pragma unroll
  for (int t = 0; t < 16; t++) ss += vals[t] * vals[t];
#pragma unroll
  for (int off = 32; off >= 1; off >>= 1) ss += __shfl_xor(ss, off);
  if ((tid & 63) == 0) red[tid >> 6] = ss;
  __syncthreads();
  float rs = rsqrtf((red[0] + red[1] + red[2] + red[3]) * (1.f / 4096.f) + 1e-5f);
  bfx8 z0 = *(const bfx8*)&zbuf[yb];
  bfx8 z1 = *(const bfx8*)&zbuf[yb + 8];
  bfx8 o0, o1;
#pragma unroll
  for (int t = 0; t < 16; t++){
    float zv = bf2f((u16)(t < 8 ? z0[t] : z1[t - 8]));
    float g = zv / (1.f + expf(-zv));
    u16 r = f2bf(vals[t] * rs * norm_w[tid * 16 + t] * g);
    if (t < 8) o0[t] = (short)r; else o1[t - 8] = (short)r;
  }
  *(bfx8*)&ynorm[yb] = o0;
  *(bfx8*)&ynorm[yb + 8] = o1;
}

extern "C" void kernel_launch(void* const* d_in, const int* in_sizes, int n_in,
                              void* d_out, int out_size, void* d_ws, size_t ws_size,
                              hipStream_t stream){
  const float* hs   = (const float*)d_in[0];
  const float* inw  = (const float*)d_in[1];
  const float* cw   = (const float*)d_in[2];
  const float* cb   = (const float*)d_in[3];
  const float* dtb  = (const float*)d_in[4];
  const float* alog = (const float*)d_in[5];
  const float* Dv   = (const float*)d_in[6];
  const float* nw   = (const float*)d_in[7];
  const float* outw = (const float*)d_in[8];

  // Workspace layout: 147,857,408 B required. z lives in d_out (exactly 64 MiB).
  const size_t REQ = 147857408ULL;
  if (ws_size < REQ){
    hipMemsetAsync(d_out, 0x42, (size_t)out_size * 4, stream);
    return;
  }
  char* ws = (char*)d_ws;
  u16*   hsb  = (u16*)  (ws + 0L);             // 33,554,432   (dead after gemm1)
  u16*   wbi  = (u16*)  (ws + 33554432L);      // 34,603,008   (dead after gemm1)
  u16*   xbc  = (u16*)  (ws + 68157440L);      // 71,303,168   (dead after conv)
  u16*   xact = (u16*)  (ws + 0L);             // 67,108,864   (overlays hsb+wbi; = ybuf = ynorm)
  u16*   stR  = (u16*)  (ws + 68157440L);      // 33,554,432   (overlays xbc)
  u16*   wbo  = (u16*)  (ws + 101711872L);     // 16,777,216   (overlays xbc tail)
  float* dtp  = (float*)(ws + 139460608L);     //  2,097,152
  float* acum = (float*)(ws + 141557760L);     //  2,097,152
  float* suma = (float*)(ws + 143654912L);     //      8,192
  u16*   bmat = (u16*)  (ws + 143663104L);     //  2,097,152
  u16*   cmat = (u16*)  (ws + 145760256L);     //  2,097,152  (end = 147,857,408)
  u16*   zbuf = (u16*)  d_out;                 // 67,108,864 = exactly out_size*4

  cvt_kernel<<<16384, 256, 0, stream>>>(hs, hsb, 4194304);
  cvt_kernel<<<16896, 256, 0, stream>>>(inw, wbi, 4325376);
  gemm_bt<0><<<dim3(64, 66), 256, 0, stream>>>(hsb, wbi, zbuf, xbc, 2048, 4096, 4352, 32);
  dt_kernel<<<256, 256, 0, stream>>>(hs, inw, dtb, dtp);
  acum_kernel<<<2048, 64, 0, stream>>>(dtp, alog, acum, suma);
  conv_kernel<<<8192, 256, 0, stream>>>(xbc, cw, cb, xact, bmat, cmat);    // xact over dead hsb+wbi
  cvt_kernel<<<8192, 256, 0, stream>>>(outw, wbo, 2097152);                // wbo over dead xbc tail
  states_kernel<<<2048, 256, 0, stream>>>(xact, bmat, acum, suma, dtp, stR);
  scan_kernel<<<128, 256, 0, stream>>>(stR, suma);
  ydiag_kernel<<<2048, 256, 0, stream>>>(cmat, bmat, xact, stR, acum, dtp, Dv, xact);  // in-place Y
  rms_kernel<<<8192, 256, 0, stream>>>(xact, zbuf, nw, xact);                           // in-place norm
  gemm_bt<1><<<dim3(64, 16), 256, 0, stream>>>(xact, wbo, d_out, d_out, 4096, 2048, 2048, 999);
}

// Round 5
// 1221.714 us; speedup vs baseline: 1.5470x; 1.1460x over previous
//
#include <hip/hip_runtime.h>

typedef unsigned short u16;
typedef __attribute__((ext_vector_type(8))) short bfx8;   // 8 bf16 in 4 VGPRs
typedef __attribute__((ext_vector_type(4))) float f32x4;
typedef __attribute__((ext_vector_type(4))) unsigned short u16x4;

__device__ __forceinline__ float bf2f(u16 u){ return __builtin_bit_cast(float, (unsigned)u << 16); }
__device__ __forceinline__ u16 f2bf(float f){
  unsigned u = __builtin_bit_cast(unsigned, f);
  return (u16)((u + 0x7fffu + ((u >> 16) & 1u)) >> 16);
}

__device__ __forceinline__ void gload_lds16(const void* g, void* l){
  __builtin_amdgcn_global_load_lds((const __attribute__((address_space(1))) void*)g,
                                   (__attribute__((address_space(3))) void*)l, 16, 0, 0);
}

// ---------------- fp32 -> bf16 convert ----------------
__global__ __launch_bounds__(256) void cvt_kernel(const float* __restrict__ in, u16* __restrict__ out, int n4){
  int i = blockIdx.x * 256 + threadIdx.x;
  if (i >= n4) return;
  f32x4 v = *(const f32x4*)&in[(long)i * 4];
  u16x4 o = { f2bf(v[0]), f2bf(v[1]), f2bf(v[2]), f2bf(v[3]) };
  *(u16x4*)&out[(long)i * 4] = o;
}

// ---------------- GEMM: C = A[M,K](bf16,rm) @ W[N,K](bf16,rm)^T ----------------
// grid = (M/128, N/128); column blocks [0,nsplit) -> out0/ld0, rest -> out1/ld1
template<int F32OUT>
__global__ __launch_bounds__(256)
void gemm_bt(const u16* __restrict__ A, const u16* __restrict__ W,
             void* __restrict__ out0, void* __restrict__ out1,
             int K, int ld0, int ld1, int nsplit)
{
  __shared__ __align__(16) u16 At[2][128 * 32];
  __shared__ __align__(16) u16 Bt[2][128 * 32];
  const int tid = threadIdx.x;
  const int bm = blockIdx.x, bn = blockIdx.y;
  const int wid = tid >> 6, lane = tid & 63;
  const int wm = (wid >> 1) << 6, wn = (wid & 1) << 6;
  const u16* ga = A + (long)(bm * 128 + (tid >> 2)) * K + (tid & 3) * 8;
  const u16* gb = W + (long)(bn * 128 + (tid >> 2)) * K + (tid & 3) * 8;
  const int ldso = (tid >> 2) * 32 + (tid & 3) * 8;
  const long gstep = (long)64 * K;

  f32x4 acc[4][4] = {};

  gload_lds16(ga, &At[0][ldso]);
  gload_lds16(ga + gstep, &At[0][2048 + ldso]);
  gload_lds16(gb, &Bt[0][ldso]);
  gload_lds16(gb + gstep, &Bt[0][2048 + ldso]);
  __syncthreads();

  const int nk = K >> 5;
  const int rr = lane & 15, ko = (lane >> 4) << 3;
  for (int kt = 0; kt < nk; ++kt){
    const int cur = kt & 1;
    if (kt + 1 < nk){
      const u16* a2 = ga + (long)(kt + 1) * 32;
      const u16* b2 = gb + (long)(kt + 1) * 32;
      gload_lds16(a2, &At[cur ^ 1][ldso]);
      gload_lds16(a2 + gstep, &At[cur ^ 1][2048 + ldso]);
      gload_lds16(b2, &Bt[cur ^ 1][ldso]);
      gload_lds16(b2 + gstep, &Bt[cur ^ 1][2048 + ldso]);
    }
    bfx8 af[4], bf[4];
#pragma unroll
    for (int mt = 0; mt < 4; mt++) af[mt] = *(const bfx8*)&At[cur][(wm + mt * 16 + rr) * 32 + ko];
#pragma unroll
    for (int nt = 0; nt < 4; nt++) bf[nt] = *(const bfx8*)&Bt[cur][(wn + nt * 16 + rr) * 32 + ko];
#pragma unroll
    for (int mt = 0; mt < 4; mt++)
#pragma unroll
      for (int nt = 0; nt < 4; nt++)
        acc[mt][nt] = __builtin_amdgcn_mfma_f32_16x16x32_bf16(af[mt], bf[nt], acc[mt][nt], 0, 0, 0);
    __syncthreads();
  }

  int bn2 = bn; void* op = out0; int ldo = ld0;
  if (bn >= nsplit){ bn2 = bn - nsplit; op = out1; ldo = ld1; }
  const int row0 = bm * 128 + wm + (lane >> 4) * 4;
  const int col0 = bn2 * 128 + wn + rr;
#pragma unroll
  for (int mt = 0; mt < 4; mt++)
#pragma unroll
    for (int nt = 0; nt < 4; nt++)
#pragma unroll
      for (int r4 = 0; r4 < 4; r4++){
        long idx = (long)(row0 + mt * 16 + r4) * ldo + col0 + nt * 16;
        if (F32OUT) ((float*)op)[idx] = acc[mt][nt][r4];
        else        ((u16*)op)[idx]  = f2bf(acc[mt][nt][r4]);
      }
}

// ---------------- dt: LDS-tiled fp32 skinny GEMM (8192x64, K=2048) + softplus + clip ----------------
__global__ __launch_bounds__(256) void dt_kernel(const float* __restrict__ hs, const float* __restrict__ w,
                                                 const float* __restrict__ dt_bias, float* __restrict__ dtp){
  __shared__ float hsS[32][66];
  __shared__ float wS[64][66];
  const int tid = threadIdx.x;
  const int j = tid & 63, rgrp = tid >> 6;
  const long row0 = (long)blockIdx.x * 32;
  const int srow = tid >> 3, sc0 = (tid & 7) * 8;     // hs staging: 32 rows x 64
  const int wrow = tid >> 2, wc0 = (tid & 3) * 16;    // w staging: 64 rows x 64
  const float* hsg = hs + (row0 + srow) * 2048 + sc0;
  const float* wg  = w + (long)(8448 + wrow) * 2048 + wc0;

  f32x4 acc[8] = {};
  for (int k0 = 0; k0 < 2048; k0 += 64){
    *(f32x4*)&hsS[srow][sc0]     = *(const f32x4*)&hsg[k0];
    *(f32x4*)&hsS[srow][sc0 + 4] = *(const f32x4*)&hsg[k0 + 4];
#pragma unroll
    for (int q = 0; q < 4; q++)
      *(f32x4*)&wS[wrow][wc0 + q * 4] = *(const f32x4*)&wg[k0 + q * 4];
    __syncthreads();
#pragma unroll
    for (int kk = 0; kk < 64; kk += 4){
      f32x4 wv = *(const f32x4*)&wS[j][kk];
#pragma unroll
      for (int r = 0; r < 8; r++){
        f32x4 hv = *(const f32x4*)&hsS[rgrp * 8 + r][kk];
        acc[r] += hv * wv;
      }
    }
    __syncthreads();
  }
  float bias = dt_bias[j];
#pragma unroll
  for (int r = 0; r < 8; r++){
    float x = acc[r][0] + acc[r][1] + acc[r][2] + acc[r][3] + bias;
    float sp = (x > 20.f) ? x : log1pf(expf(x));
    sp = fminf(fmaxf(sp, 0.f), 100.f);
    dtp[(row0 + rgrp * 8 + r) * 64 + j] = sp;
  }
}

// ---------------- per (b,h,chunk): Adt cumsum (fp32) ----------------
__global__ __launch_bounds__(64) void acum_kernel(const float* __restrict__ dtp, const float* __restrict__ A_log,
                                                  float* __restrict__ acum, float* __restrict__ suma){
  int bid = blockIdx.x;                 // ((b*64+h)*16+c)
  int c = bid & 15, h = (bid >> 4) & 63, b = bid >> 10;
  int lane = threadIdx.x;
  float Ah = -expf(A_log[h]);
  long base = ((long)(b * 4096 + c * 256)) * 64 + h;
  float v[4]; float s = 0.f;
#pragma unroll
  for (int i = 0; i < 4; i++){ float adt = dtp[base + (lane * 4 + i) * 64] * Ah; s += adt; v[i] = s; }
  float tot = s, run = s;
  for (int off = 1; off < 64; off <<= 1){ float u = __shfl_up(run, off); if (lane >= off) run += u; }
  float excl = run - tot;
  long ob = (long)bid * 256 + lane * 4;
#pragma unroll
  for (int i = 0; i < 4; i++) acum[ob + i] = excl + v[i];
  if (lane == 63) suma[bid] = run;
}

// ---------------- depthwise conv + bias + silu + split ----------------
__global__ __launch_bounds__(256) void conv_kernel(const u16* __restrict__ xbc, const float* __restrict__ cw,
                                                   const float* __restrict__ cb,
                                                   u16* __restrict__ xact,
                                                   u16* __restrict__ bmat, u16* __restrict__ cmat){
  int pos = blockIdx.x;                 // b*4096 + l
  int l = pos & 4095;
  for (int ch = threadIdx.x; ch < 4352; ch += 256){
    float acc = cb[ch];
#pragma unroll
    for (int k = 0; k < 4; k++){
      int lp = l + k - 3;
      if (lp >= 0) acc += cw[ch * 4 + k] * bf2f(xbc[(long)(pos + k - 3) * 4352 + ch]);
    }
    float val = acc / (1.f + expf(-acc));
    if (ch < 4096)      xact[(long)pos * 4096 + ch] = f2bf(val);
    else if (ch < 4224) bmat[(long)pos * 128 + ch - 4096] = f2bf(val);
    else                cmat[(long)pos * 128 + ch - 4224] = f2bf(val);
  }
}

// ---------------- per (b,c,h): chunk end-state E = (X*dt*decay)^T @ B  (bf16 out) ----------------
__global__ __launch_bounds__(256) void states_kernel(const u16* __restrict__ xact, const u16* __restrict__ bmat,
                                                     const float* __restrict__ acum, const float* __restrict__ suma,
                                                     const float* __restrict__ dtp, u16* __restrict__ stR){
  __shared__ __align__(16) u16 XdT[64 * 264];
  __shared__ __align__(16) u16 BT[128 * 264];
  __shared__ float fac[256];
  int bid = blockIdx.x;                 // ((b*16+c)*64+h)
  int h = bid & 63, c = (bid >> 6) & 15, b = bid >> 10;
  int tid = threadIdx.x;
  long rowbase = (long)b * 4096 + c * 256;
  long aco = ((long)((b * 64 + h) * 16 + c)) * 256;
  float sA = suma[(b * 64 + h) * 16 + c];
  fac[tid] = dtp[(rowbase + tid) * 64 + h] * expf(sA - acum[aco + tid]);
  __syncthreads();
  for (int idx = tid; idx < 16384; idx += 256){
    int l = idx >> 6, p = idx & 63;
    XdT[p * 264 + l] = f2bf(bf2f(xact[(rowbase + l) * 4096 + h * 64 + p]) * fac[l]);
  }
  for (int idx = tid; idx < 32768; idx += 256){
    int l = idx >> 7, n = idx & 127;
    BT[n * 264 + l] = bmat[(rowbase + l) * 128 + n];
  }
  __syncthreads();
  int wid = tid >> 6, lane = tid & 63;
  int rr = lane & 15, ko = (lane >> 4) * 8;
  f32x4 acc[8] = {};
#pragma unroll
  for (int ks = 0; ks < 8; ks++){
    bfx8 a = *(const bfx8*)&XdT[(wid * 16 + rr) * 264 + ks * 32 + ko];
#pragma unroll
    for (int nt = 0; nt < 8; nt++){
      bfx8 bb = *(const bfx8*)&BT[(nt * 16 + rr) * 264 + ks * 32 + ko];
      acc[nt] = __builtin_amdgcn_mfma_f32_16x16x32_bf16(a, bb, acc[nt], 0, 0, 0);
    }
  }
  long ob = (long)bid * 8192;
#pragma unroll
  for (int nt = 0; nt < 8; nt++)
#pragma unroll
    for (int r4 = 0; r4 < 4; r4++){
      int p = wid * 16 + (lane >> 4) * 4 + r4;
      stR[ob + p * 128 + nt * 16 + rr] = f2bf(acc[nt][r4]);
    }
}

// ---------------- inter-chunk scan: in-place E -> R (prev_states), bf16 ----------------
__global__ __launch_bounds__(256) void scan_kernel(u16* stR, const float* __restrict__ suma){
  int bh = blockIdx.x; int b = bh >> 6, h = bh & 63;
  int tid = threadIdx.x;
  f32x4 R[8] = {};
  for (int c = 0; c < 16; c++){
    long base = ((long)((b * 16 + c) * 64 + h)) * 8192;
    float sc = expf(suma[(b * 64 + h) * 16 + c]);
#pragma unroll
    for (int i = 0; i < 8; i++){
      long off = base + i * 1024 + tid * 4;
      u16x4 e4 = *(const u16x4*)&stR[off];
      u16x4 o = { f2bf(R[i][0]), f2bf(R[i][1]), f2bf(R[i][2]), f2bf(R[i][3]) };
      *(u16x4*)&stR[off] = o;
#pragma unroll
      for (int t = 0; t < 4; t++) R[i][t] = sc * R[i][t] + bf2f(e4[t]);
    }
  }
}

// ---------------- per (b,c,h): Y = (CB^T ∘ L) @ Xdt + exp(Acum)*(C @ R^T) + x*D ----------------
// C fragments live in registers (loaded direct from global); B staged in 64-row quarters.
// LDS ~74 KB -> 2 blocks/CU. ybuf may alias xact (in-place, block-owned region).
__global__ __launch_bounds__(256, 2) void ydiag_kernel(const u16* __restrict__ cmat, const u16* __restrict__ bmat,
                                                       const u16* xact,
                                                       const u16* __restrict__ rbuf, const float* __restrict__ acum,
                                                       const float* __restrict__ dtp,
                                                       const float* __restrict__ Dv, u16* ybuf){
  __shared__ __align__(16) u16 Bq[64 * 136];
  __shared__ __align__(16) u16 XdT[64 * 264];
  __shared__ __align__(16) u16 Sb[4][64 * 40];
  __shared__ float acL[256];
  __shared__ float dtl[256];
  int bid = blockIdx.x;                 // ((b*16+c)*64+h)
  int h = bid & 63, c = (bid >> 6) & 15, b = bid >> 10;
  int tid = threadIdx.x, wid = tid >> 6, lane = tid & 63;
  long rowbase = (long)b * 4096 + c * 256;
  long aco = ((long)((b * 64 + h) * 16 + c)) * 256;
  acL[tid] = acum[aco + tid];
  dtl[tid] = dtp[(rowbase + tid) * 64 + h];
  __syncthreads();

  int rr = lane & 15, ko = (lane >> 4) * 8;

  // C fragments for this wave's 64 l-rows: [lt][kk], direct from global
  bfx8 cfrag[4][4];
#pragma unroll
  for (int lt = 0; lt < 4; lt++)
#pragma unroll
    for (int kk = 0; kk < 4; kk++)
      cfrag[lt][kk] = *(const bfx8*)&cmat[(rowbase + wid * 64 + lt * 16 + rr) * 128 + kk * 32 + ko];

  // stage XdT (transposed x*dt)
  for (int idx = tid; idx < 16384; idx += 256){
    int l = idx >> 6, p = idx & 63;
    XdT[p * 264 + l] = f2bf(bf2f(xact[(rowbase + l) * 4096 + h * 64 + p]) * dtl[l]);
  }

  f32x4 acc[4][4] = {};

  // Y_off = C @ R^T (R from global), scaled by exp(acum[l])
  long rb = (long)bid * 8192;
#pragma unroll
  for (int kk = 0; kk < 4; kk++){
#pragma unroll
    for (int pt = 0; pt < 4; pt++){
      bfx8 bb = *(const bfx8*)&rbuf[rb + (pt * 16 + rr) * 128 + kk * 32 + ko];
#pragma unroll
      for (int lt = 0; lt < 4; lt++) acc[lt][pt] = __builtin_amdgcn_mfma_f32_16x16x32_bf16(cfrag[lt][kk], bb, acc[lt][pt], 0, 0, 0);
    }
  }
#pragma unroll
  for (int lt = 0; lt < 4; lt++)
#pragma unroll
    for (int r4 = 0; r4 < 4; r4++){
      float e = expf(acL[wid * 64 + lt * 16 + (lane >> 4) * 4 + r4]);
#pragma unroll
      for (int pt = 0; pt < 4; pt++) acc[lt][pt][r4] *= e;
    }

  const int nsp = 2 * (wid + 1);   // causal: wave w needs s-pairs 0..2w+1
  for (int q = 0; q < 4; q++){
    __syncthreads();
    // stage B rows [q*64, q*64+64)
    for (int v = tid; v < 1024; v += 256){
      int s = v >> 4, no = (v & 15) * 8;
      *(bfx8*)&Bq[s * 136 + no] = *(const bfx8*)&bmat[(rowbase + q * 64 + s) * 128 + no];
    }
    __syncthreads();
#pragma unroll
    for (int sub = 0; sub < 2; sub++){
      int sp = q * 2 + sub;
      if (sp >= nsp) continue;           // wave-uniform
      int s0 = sp * 32, srow = sub * 32;
      f32x4 sacc[2][4] = {};
#pragma unroll
      for (int kk = 0; kk < 4; kk++){
#pragma unroll
        for (int st = 0; st < 2; st++){
          bfx8 bb = *(const bfx8*)&Bq[(srow + st * 16 + rr) * 136 + kk * 32 + ko];
#pragma unroll
          for (int lt = 0; lt < 4; lt++) sacc[st][lt] = __builtin_amdgcn_mfma_f32_16x16x32_bf16(cfrag[lt][kk], bb, sacc[st][lt], 0, 0, 0);
        }
      }
#pragma unroll
      for (int st = 0; st < 2; st++)
#pragma unroll
        for (int lt = 0; lt < 4; lt++)
#pragma unroll
          for (int r4 = 0; r4 < 4; r4++){
            int lrow = wid * 64 + lt * 16 + (lane >> 4) * 4 + r4;
            int scol = s0 + st * 16 + rr;
            float vv = (scol <= lrow) ? sacc[st][lt][r4] * expf(acL[lrow] - acL[scol]) : 0.f;
            Sb[wid][(lt * 16 + (lane >> 4) * 4 + r4) * 40 + st * 16 + rr] = f2bf(vv);
          }
      asm volatile("s_waitcnt lgkmcnt(0)" ::: "memory");
      __builtin_amdgcn_sched_barrier(0);
#pragma unroll
      for (int lt = 0; lt < 4; lt++){
        bfx8 a1 = *(const bfx8*)&Sb[wid][(lt * 16 + rr) * 40 + ko];
#pragma unroll
        for (int pt = 0; pt < 4; pt++){
          bfx8 bb = *(const bfx8*)&XdT[(pt * 16 + rr) * 264 + s0 + ko];
          acc[lt][pt] = __builtin_amdgcn_mfma_f32_16x16x32_bf16(a1, bb, acc[lt][pt], 0, 0, 0);
        }
      }
    }
  }
  float Dh = Dv[h];
#pragma unroll
  for (int lt = 0; lt < 4; lt++)
#pragma unroll
    for (int pt = 0; pt < 4; pt++)
#pragma unroll
      for (int r4 = 0; r4 < 4; r4++){
        int lrow = wid * 64 + lt * 16 + (lane >> 4) * 4 + r4;
        int pcol = pt * 16 + rr;
        long gi = (rowbase + lrow) * 4096 + h * 64 + pcol;
        ybuf[gi] = f2bf(acc[lt][pt][r4] + bf2f(xact[gi]) * Dh);
      }
}

// ---------------- RMSNorm + silu(z) gate (may write in place over ybuf) ----------------
__global__ __launch_bounds__(256) void rms_kernel(const u16* ybuf, const u16* zbuf,
                                                  const float* __restrict__ norm_w, u16* ynorm){
  __shared__ float red[4];
  long row = blockIdx.x;
  int tid = threadIdx.x;
  long yb = row * 4096 + tid * 16;
  bfx8 v0 = *(const bfx8*)&ybuf[yb];
  bfx8 v1 = *(const bfx8*)&ybuf[yb + 8];
  float vals[16];
#pragma unroll
  for (int t = 0; t < 8; t++){ vals[t] = bf2f((u16)v0[t]); vals[8 + t] = bf2f((u16)v1[t]); }
  float ss = 0.f;
#pragma unroll
  for (int t = 0; t < 16; t++) ss += vals[t] * vals[t];
#pragma unroll
  for (int off = 32; off >= 1; off >>= 1) ss += __shfl_xor(ss, off);
  if ((tid & 63) == 0) red[tid >> 6] = ss;
  __syncthreads();
  float rs = rsqrtf((red[0] + red[1] + red[2] + red[3]) * (1.f / 4096.f) + 1e-5f);
  bfx8 z0 = *(const bfx8*)&zbuf[yb];
  bfx8 z1 = *(const bfx8*)&zbuf[yb + 8];
  bfx8 o0, o1;
#pragma unroll
  for (int t = 0; t < 16; t++){
    float zv = bf2f((u16)(t < 8 ? z0[t] : z1[t - 8]));
    float g = zv / (1.f + expf(-zv));
    u16 r = f2bf(vals[t] * rs * norm_w[tid * 16 + t] * g);
    if (t < 8) o0[t] = (short)r; else o1[t - 8] = (short)r;
  }
  *(bfx8*)&ynorm[yb] = o0;
  *(bfx8*)&ynorm[yb + 8] = o1;
}

extern "C" void kernel_launch(void* const* d_in, const int* in_sizes, int n_in,
                              void* d_out, int out_size, void* d_ws, size_t ws_size,
                              hipStream_t stream){
  const float* hs   = (const float*)d_in[0];
  const float* inw  = (const float*)d_in[1];
  const float* cw   = (const float*)d_in[2];
  const float* cb   = (const float*)d_in[3];
  const float* dtb  = (const float*)d_in[4];
  const float* alog = (const float*)d_in[5];
  const float* Dv   = (const float*)d_in[6];
  const float* nw   = (const float*)d_in[7];
  const float* outw = (const float*)d_in[8];

  // Workspace layout: 147,857,408 B required. z lives in d_out (exactly 64 MiB).
  const size_t REQ = 147857408ULL;
  if (ws_size < REQ){
    hipMemsetAsync(d_out, 0x42, (size_t)out_size * 4, stream);
    return;
  }
  char* ws = (char*)d_ws;
  u16*   hsb  = (u16*)  (ws + 0L);             // 33,554,432   (dead after gemm1)
  u16*   wbi  = (u16*)  (ws + 33554432L);      // 34,603,008   (dead after gemm1)
  u16*   xbc  = (u16*)  (ws + 68157440L);      // 71,303,168   (dead after conv)
  u16*   xact = (u16*)  (ws + 0L);             // 67,108,864   (overlays hsb+wbi; = ybuf = ynorm)
  u16*   stR  = (u16*)  (ws + 68157440L);      // 33,554,432   (overlays xbc)
  u16*   wbo  = (u16*)  (ws + 101711872L);     // 16,777,216   (overlays xbc tail)
  float* dtp  = (float*)(ws + 139460608L);     //  2,097,152
  float* acum = (float*)(ws + 141557760L);     //  2,097,152
  float* suma = (float*)(ws + 143654912L);     //      8,192
  u16*   bmat = (u16*)  (ws + 143663104L);     //  2,097,152
  u16*   cmat = (u16*)  (ws + 145760256L);     //  2,097,152  (end = 147,857,408)
  u16*   zbuf = (u16*)  d_out;                 // 67,108,864 = exactly out_size*4

  cvt_kernel<<<16384, 256, 0, stream>>>(hs, hsb, 4194304);
  cvt_kernel<<<16896, 256, 0, stream>>>(inw, wbi, 4325376);
  gemm_bt<0><<<dim3(64, 66), 256, 0, stream>>>(hsb, wbi, zbuf, xbc, 2048, 4096, 4352, 32);
  dt_kernel<<<256, 256, 0, stream>>>(hs, inw, dtb, dtp);
  acum_kernel<<<2048, 64, 0, stream>>>(dtp, alog, acum, suma);
  conv_kernel<<<8192, 256, 0, stream>>>(xbc, cw, cb, xact, bmat, cmat);    // xact over dead hsb+wbi
  cvt_kernel<<<8192, 256, 0, stream>>>(outw, wbo, 2097152);                // wbo over dead xbc tail
  states_kernel<<<2048, 256, 0, stream>>>(xact, bmat, acum, suma, dtp, stR);
  scan_kernel<<<128, 256, 0, stream>>>(stR, suma);
  ydiag_kernel<<<2048, 256, 0, stream>>>(cmat, bmat, xact, stR, acum, dtp, Dv, xact);  // in-place Y
  rms_kernel<<<8192, 256, 0, stream>>>(xact, zbuf, nw, xact);                           // in-place norm
  gemm_bt<1><<<dim3(64, 16), 256, 0, stream>>>(xact, wbo, d_out, d_out, 4096, 2048, 2048, 999);
}

// Round 7
// 1133.774 us; speedup vs baseline: 1.6669x; 1.0776x over previous
//
#include <hip/hip_runtime.h>

typedef unsigned short u16;
typedef __attribute__((ext_vector_type(8))) short bfx8;   // 8 bf16 in 4 VGPRs
typedef __attribute__((ext_vector_type(4))) float f32x4;
typedef __attribute__((ext_vector_type(4))) unsigned short u16x4;

__device__ __forceinline__ float bf2f(u16 u){ return __builtin_bit_cast(float, (unsigned)u << 16); }
__device__ __forceinline__ u16 f2bf(float f){
  unsigned u = __builtin_bit_cast(unsigned, f);
  return (u16)((u + 0x7fffu + ((u >> 16) & 1u)) >> 16);
}

__device__ __forceinline__ void gload_lds16(const void* g, void* l){
  __builtin_amdgcn_global_load_lds((const __attribute__((address_space(1))) void*)g,
                                   (__attribute__((address_space(3))) void*)l, 16, 0, 0);
}

// ---------------- fp32 -> bf16 convert ----------------
__global__ __launch_bounds__(256) void cvt_kernel(const float* __restrict__ in, u16* __restrict__ out, int n4){
  int i = blockIdx.x * 256 + threadIdx.x;
  if (i >= n4) return;
  f32x4 v = *(const f32x4*)&in[(long)i * 4];
  u16x4 o = { f2bf(v[0]), f2bf(v[1]), f2bf(v[2]), f2bf(v[3]) };
  *(u16x4*)&out[(long)i * 4] = o;
}

// ---------------- GEMM: C = A[M,K](bf16,rm) @ W[N,K](bf16,rm)^T ----------------
template<int F32OUT>
__global__ __launch_bounds__(256)
void gemm_bt(const u16* __restrict__ A, const u16* __restrict__ W,
             void* __restrict__ out0, void* __restrict__ out1,
             int K, int ld0, int ld1, int nsplit)
{
  __shared__ __align__(16) u16 At[2][128 * 32];
  __shared__ __align__(16) u16 Bt[2][128 * 32];
  const int tid = threadIdx.x;
  const int bm = blockIdx.x, bn = blockIdx.y;
  const int wid = tid >> 6, lane = tid & 63;
  const int wm = (wid >> 1) << 6, wn = (wid & 1) << 6;
  const u16* ga = A + (long)(bm * 128 + (tid >> 2)) * K + (tid & 3) * 8;
  const u16* gb = W + (long)(bn * 128 + (tid >> 2)) * K + (tid & 3) * 8;
  const int ldso = (tid >> 2) * 32 + (tid & 3) * 8;
  const long gstep = (long)64 * K;

  f32x4 acc[4][4] = {};

  gload_lds16(ga, &At[0][ldso]);
  gload_lds16(ga + gstep, &At[0][2048 + ldso]);
  gload_lds16(gb, &Bt[0][ldso]);
  gload_lds16(gb + gstep, &Bt[0][2048 + ldso]);
  __syncthreads();

  const int nk = K >> 5;
  const int rr = lane & 15, ko = (lane >> 4) << 3;
  for (int kt = 0; kt < nk; ++kt){
    const int cur = kt & 1;
    if (kt + 1 < nk){
      const u16* a2 = ga + (long)(kt + 1) * 32;
      const u16* b2 = gb + (long)(kt + 1) * 32;
      gload_lds16(a2, &At[cur ^ 1][ldso]);
      gload_lds16(a2 + gstep, &At[cur ^ 1][2048 + ldso]);
      gload_lds16(b2, &Bt[cur ^ 1][ldso]);
      gload_lds16(b2 + gstep, &Bt[cur ^ 1][2048 + ldso]);
    }
    bfx8 af[4], bf[4];
#pragma unroll
    for (int mt = 0; mt < 4; mt++) af[mt] = *(const bfx8*)&At[cur][(wm + mt * 16 + rr) * 32 + ko];
#pragma unroll
    for (int nt = 0; nt < 4; nt++) bf[nt] = *(const bfx8*)&Bt[cur][(wn + nt * 16 + rr) * 32 + ko];
#pragma unroll
    for (int mt = 0; mt < 4; mt++)
#pragma unroll
      for (int nt = 0; nt < 4; nt++)
        acc[mt][nt] = __builtin_amdgcn_mfma_f32_16x16x32_bf16(af[mt], bf[nt], acc[mt][nt], 0, 0, 0);
    __syncthreads();
  }

  int bn2 = bn; void* op = out0; int ldo = ld0;
  if (bn >= nsplit){ bn2 = bn - nsplit; op = out1; ldo = ld1; }
  const int row0 = bm * 128 + wm + (lane >> 4) * 4;
  const int col0 = bn2 * 128 + wn + rr;
#pragma unroll
  for (int mt = 0; mt < 4; mt++)
#pragma unroll
    for (int nt = 0; nt < 4; nt++)
#pragma unroll
      for (int r4 = 0; r4 < 4; r4++){
        long idx = (long)(row0 + mt * 16 + r4) * ldo + col0 + nt * 16;
        if (F32OUT) ((float*)op)[idx] = acc[mt][nt][r4];
        else        ((u16*)op)[idx]  = f2bf(acc[mt][nt][r4]);
      }
}

// ---------------- dt: LDS-tiled fp32 skinny GEMM (8192x64, K=2048) + softplus + clip ----------------
__global__ __launch_bounds__(256) void dt_kernel(const float* __restrict__ hs, const float* __restrict__ w,
                                                 const float* __restrict__ dt_bias, float* __restrict__ dtp){
  __shared__ float hsS[32][66];
  __shared__ float wS[64][66];
  const int tid = threadIdx.x;
  const int j = tid & 63, rgrp = tid >> 6;
  const long row0 = (long)blockIdx.x * 32;
  const int srow = tid >> 3, sc0 = (tid & 7) * 8;
  const int wrow = tid >> 2, wc0 = (tid & 3) * 16;
  const float* hsg = hs + (row0 + srow) * 2048 + sc0;
  const float* wg  = w + (long)(8448 + wrow) * 2048 + wc0;

  f32x4 acc[8] = {};
  for (int k0 = 0; k0 < 2048; k0 += 64){
    *(f32x4*)&hsS[srow][sc0]     = *(const f32x4*)&hsg[k0];
    *(f32x4*)&hsS[srow][sc0 + 4] = *(const f32x4*)&hsg[k0 + 4];
#pragma unroll
    for (int q = 0; q < 4; q++)
      *(f32x4*)&wS[wrow][wc0 + q * 4] = *(const f32x4*)&wg[k0 + q * 4];
    __syncthreads();
#pragma unroll
    for (int kk = 0; kk < 64; kk += 4){
      f32x4 wv = *(const f32x4*)&wS[j][kk];
#pragma unroll
      for (int r = 0; r < 8; r++){
        f32x4 hv = *(const f32x4*)&hsS[rgrp * 8 + r][kk];
        acc[r] += hv * wv;
      }
    }
    __syncthreads();
  }
  float bias = dt_bias[j];
#pragma unroll
  for (int r = 0; r < 8; r++){
    float x = acc[r][0] + acc[r][1] + acc[r][2] + acc[r][3] + bias;
    float sp = (x > 20.f) ? x : log1pf(expf(x));
    sp = fminf(fmaxf(sp, 0.f), 100.f);
    dtp[(row0 + rgrp * 8 + r) * 64 + j] = sp;
  }
}

// ---------------- per (b,h,chunk): Adt cumsum (fp32) ----------------
__global__ __launch_bounds__(64) void acum_kernel(const float* __restrict__ dtp, const float* __restrict__ A_log,
                                                  float* __restrict__ acum, float* __restrict__ suma){
  int bid = blockIdx.x;                 // ((b*64+h)*16+c)
  int c = bid & 15, h = (bid >> 4) & 63, b = bid >> 10;
  int lane = threadIdx.x;
  float Ah = -expf(A_log[h]);
  long base = ((long)(b * 4096 + c * 256)) * 64 + h;
  float v[4]; float s = 0.f;
#pragma unroll
  for (int i = 0; i < 4; i++){ float adt = dtp[base + (lane * 4 + i) * 64] * Ah; s += adt; v[i] = s; }
  float tot = s, run = s;
  for (int off = 1; off < 64; off <<= 1){ float u = __shfl_up(run, off); if (lane >= off) run += u; }
  float excl = run - tot;
  long ob = (long)bid * 256 + lane * 4;
#pragma unroll
  for (int i = 0; i < 4; i++) acum[ob + i] = excl + v[i];
  if (lane == 63) suma[bid] = run;
}

// ---------------- depthwise conv + bias + silu + split (vectorized: 8 ch/thread) ----------------
__global__ __launch_bounds__(256) void conv_kernel(const u16* __restrict__ xbc, const float* __restrict__ cw,
                                                   const float* __restrict__ cb,
                                                   u16* __restrict__ xact,
                                                   u16* __restrict__ bmat, u16* __restrict__ cmat){
  int pos = blockIdx.x;                 // b*4096 + l
  int l = pos & 4095;
  for (int cg = threadIdx.x; cg < 544; cg += 256){
    int ch = cg * 8;
    f32x4 cwv[8];
#pragma unroll
    for (int t = 0; t < 8; t++) cwv[t] = *(const f32x4*)&cw[(ch + t) * 4];
    float acc[8];
#pragma unroll
    for (int t = 0; t < 8; t++) acc[t] = cb[ch + t];
#pragma unroll
    for (int k = 0; k < 4; k++){
      int lp = l + k - 3;
      if (lp < 0) continue;
      bfx8 xv = *(const bfx8*)&xbc[(long)(pos + k - 3) * 4352 + ch];
#pragma unroll
      for (int t = 0; t < 8; t++) acc[t] += cwv[t][k] * bf2f((u16)xv[t]);
    }
    bfx8 o;
#pragma unroll
    for (int t = 0; t < 8; t++){
      float val = acc[t] / (1.f + expf(-acc[t]));
      o[t] = (short)f2bf(val);
    }
    if (ch < 4096)      *(bfx8*)&xact[(long)pos * 4096 + ch] = o;
    else if (ch < 4224) *(bfx8*)&bmat[(long)pos * 128 + ch - 4096] = o;
    else                *(bfx8*)&cmat[(long)pos * 128 + ch - 4224] = o;
  }
}

// ---------------- bmat[b*4096+l][128] -> bmatT[b][n][4096] ----------------
__global__ __launch_bounds__(256) void bt_transpose(const u16* __restrict__ bmat, u16* __restrict__ bmatT){
  __shared__ u16 T[128 * 136];
  int bx = blockIdx.x;                  // b*32 + ltile
  int b = bx >> 5, lt = bx & 31;
  int l0 = lt * 128;
  int tid = threadIdx.x;
  for (int idx = tid; idx < 2048; idx += 256){
    int lrow = idx >> 4, ns = (idx & 15) * 8;
    *(bfx8*)&T[lrow * 136 + ns] = *(const bfx8*)&bmat[((long)b * 4096 + l0 + lrow) * 128 + ns];
  }
  __syncthreads();
  for (int idx = tid; idx < 2048; idx += 256){
    int nrow = idx >> 4, ls = (idx & 15) * 8;   // ls = starting l within this 128-l tile
    bfx8 o;
#pragma unroll
    for (int j = 0; j < 8; j++) o[j] = (short)T[(ls + j) * 136 + nrow];
    *(bfx8*)&bmatT[(long)b * 524288 + (long)nrow * 4096 + l0 + ls] = o;
  }
}

// ---------------- per (b,c,h): chunk end-state E = (X*dt*decay)^T @ B  (bf16 out) ----------------
// B-fragments direct from global bmatT (L2-hot). LDS ~35 KB -> 4 blocks/CU.
__global__ __launch_bounds__(256, 4) void states_kernel(const u16* __restrict__ xact, const u16* __restrict__ bmatT,
                                                        const float* __restrict__ acum, const float* __restrict__ suma,
                                                        const float* __restrict__ dtp, u16* __restrict__ stR){
  __shared__ __align__(16) u16 XdT[64 * 264];
  __shared__ float fac[256];
  int bid = blockIdx.x;                 // ((b*16+c)*64+h)
  int h = bid & 63, c = (bid >> 6) & 15, b = bid >> 10;
  int tid = threadIdx.x;
  long rowbase = (long)b * 4096 + c * 256;
  long aco = ((long)((b * 64 + h) * 16 + c)) * 256;
  float sA = suma[(b * 64 + h) * 16 + c];
  fac[tid] = dtp[(rowbase + tid) * 64 + h] * expf(sA - acum[aco + tid]);
  __syncthreads();
  for (int idx = tid; idx < 2048; idx += 256){
    int l = idx >> 3, ps = (idx & 7) * 8;
    bfx8 xv = *(const bfx8*)&xact[(rowbase + l) * 4096 + h * 64 + ps];
#pragma unroll
    for (int j = 0; j < 8; j++)
      XdT[(ps + j) * 264 + l] = f2bf(bf2f((u16)xv[j]) * fac[l]);
  }
  __syncthreads();
  int wid = tid >> 6, lane = tid & 63;
  int rr = lane & 15, ko = (lane >> 4) * 8;
  const u16* btb = bmatT + (long)b * 524288 + c * 256;
  f32x4 acc[8] = {};
#pragma unroll
  for (int ks = 0; ks < 8; ks++){
    bfx8 a = *(const bfx8*)&XdT[(wid * 16 + rr) * 264 + ks * 32 + ko];
#pragma unroll
    for (int nt = 0; nt < 8; nt++){
      bfx8 bb = *(const bfx8*)&btb[(long)(nt * 16 + rr) * 4096 + ks * 32 + ko];
      acc[nt] = __builtin_amdgcn_mfma_f32_16x16x32_bf16(a, bb, acc[nt], 0, 0, 0);
    }
  }
  long ob = (long)bid * 8192;
#pragma unroll
  for (int nt = 0; nt < 8; nt++)
#pragma unroll
    for (int r4 = 0; r4 < 4; r4++){
      int p = wid * 16 + (lane >> 4) * 4 + r4;
      stR[ob + p * 128 + nt * 16 + rr] = f2bf(acc[nt][r4]);
    }
}

// ---------------- inter-chunk scan: in-place E -> R (prev_states), bf16 ----------------
__global__ __launch_bounds__(256) void scan_kernel(u16* stR, const float* __restrict__ suma){
  int bh = blockIdx.x; int b = bh >> 6, h = bh & 63;
  int tid = threadIdx.x;
  f32x4 R[8] = {};
  for (int c = 0; c < 16; c++){
    long base = ((long)((b * 16 + c) * 64 + h)) * 8192;
    float sc = expf(suma[(b * 64 + h) * 16 + c]);
#pragma unroll
    for (int i = 0; i < 8; i++){
      long off = base + i * 1024 + tid * 4;
      u16x4 e4 = *(const u16x4*)&stR[off];
      u16x4 o = { f2bf(R[i][0]), f2bf(R[i][1]), f2bf(R[i][2]), f2bf(R[i][3]) };
      *(u16x4*)&stR[off] = o;
#pragma unroll
      for (int t = 0; t < 4; t++) R[i][t] = sc * R[i][t] + bf2f(e4[t]);
    }
  }
}

// ---------------- per (b,c,h): Y = (CB^T ∘ L) @ Xdt + exp(Acum)*(C @ R^T) + x*D ----------------
// C/B fragments direct from global (L2-hot 2MB each); XdT staged in 64-l quarters.
// LDS ~29 KB; ybuf may alias xact (in-place, block-owned region).
__global__ __launch_bounds__(256, 3) void ydiag_kernel(const u16* __restrict__ cmat, const u16* __restrict__ bmat,
                                                       const u16* xact,
                                                       const u16* __restrict__ rbuf, const float* __restrict__ acum,
                                                       const float* __restrict__ dtp,
                                                       const float* __restrict__ Dv, u16* ybuf){
  __shared__ __align__(16) u16 XdTq[64 * 72];
  __shared__ __align__(16) u16 Sb[4][64 * 36];
  __shared__ float acL[256];
  __shared__ float dtl[256];
  int bid = blockIdx.x;                 // ((b*16+c)*64+h)
  int h = bid & 63, c = (bid >> 6) & 15, b = bid >> 10;
  int tid = threadIdx.x, wid = tid >> 6, lane = tid & 63;
  long rowbase = (long)b * 4096 + c * 256;
  long aco = ((long)((b * 64 + h) * 16 + c)) * 256;
  acL[tid] = acum[aco + tid];
  dtl[tid] = dtp[(rowbase + tid) * 64 + h];
  __syncthreads();

  int rr = lane & 15, ko = (lane >> 4) * 8;
  f32x4 acc[4][4] = {};

  // Y_off = C @ R^T (C, R from global), scaled by exp(acum[l])
  long rb = (long)bid * 8192;
#pragma unroll
  for (int kk = 0; kk < 4; kk++){
    bfx8 cf[4];
#pragma unroll
    for (int lt = 0; lt < 4; lt++)
      cf[lt] = *(const bfx8*)&cmat[(rowbase + wid * 64 + lt * 16 + rr) * 128 + kk * 32 + ko];
#pragma unroll
    for (int pt = 0; pt < 4; pt++){
      bfx8 bb = *(const bfx8*)&rbuf[rb + (pt * 16 + rr) * 128 + kk * 32 + ko];
#pragma unroll
      for (int lt = 0; lt < 4; lt++) acc[lt][pt] = __builtin_amdgcn_mfma_f32_16x16x32_bf16(cf[lt], bb, acc[lt][pt], 0, 0, 0);
    }
  }
#pragma unroll
  for (int lt = 0; lt < 4; lt++)
#pragma unroll
    for (int r4 = 0; r4 < 4; r4++){
      float e = expf(acL[wid * 64 + lt * 16 + (lane >> 4) * 4 + r4]);
#pragma unroll
      for (int pt = 0; pt < 4; pt++) acc[lt][pt][r4] *= e;
    }

  const int nsp = 2 * (wid + 1);   // causal: wave w needs s-pairs 0..2w+1
  for (int q = 0; q < 4; q++){
    __syncthreads();
    // stage XdT quarter: l in [q*64, q*64+64), scaled by dt[l]
    for (int idx = tid; idx < 512; idx += 256){
      int lq = idx >> 3, ps = (idx & 7) * 8;
      int l = q * 64 + lq;
      bfx8 xv = *(const bfx8*)&xact[(rowbase + l) * 4096 + h * 64 + ps];
#pragma unroll
      for (int j = 0; j < 8; j++)
        XdTq[(ps + j) * 72 + lq] = f2bf(bf2f((u16)xv[j]) * dtl[l]);
    }
    __syncthreads();
#pragma unroll
    for (int sub = 0; sub < 2; sub++){
      int sp = q * 2 + sub;
      if (sp >= nsp) continue;           // wave-uniform
      int s0 = sp * 32;
      f32x4 sacc[2][4] = {};
#pragma unroll
      for (int kk = 0; kk < 4; kk++){
        bfx8 cf[4];
#pragma unroll
        for (int lt = 0; lt < 4; lt++)
          cf[lt] = *(const bfx8*)&cmat[(rowbase + wid * 64 + lt * 16 + rr) * 128 + kk * 32 + ko];
#pragma unroll
        for (int st = 0; st < 2; st++){
          bfx8 bb = *(const bfx8*)&bmat[(rowbase + s0 + st * 16 + rr) * 128 + kk * 32 + ko];
#pragma unroll
          for (int lt = 0; lt < 4; lt++) sacc[st][lt] = __builtin_amdgcn_mfma_f32_16x16x32_bf16(cf[lt], bb, sacc[st][lt], 0, 0, 0);
        }
      }
#pragma unroll
      for (int st = 0; st < 2; st++)
#pragma unroll
        for (int lt = 0; lt < 4; lt++)
#pragma unroll
          for (int r4 = 0; r4 < 4; r4++){
            int lrow = wid * 64 + lt * 16 + (lane >> 4) * 4 + r4;
            int scol = s0 + st * 16 + rr;
            float vv = (scol <= lrow) ? sacc[st][lt][r4] * expf(acL[lrow] - acL[scol]) : 0.f;
            Sb[wid][(lt * 16 + (lane >> 4) * 4 + r4) * 36 + st * 16 + rr] = f2bf(vv);
          }
      asm volatile("s_waitcnt lgkmcnt(0)" ::: "memory");
      __builtin_amdgcn_sched_barrier(0);
#pragma unroll
      for (int lt = 0; lt < 4; lt++){
        bfx8 a1 = *(const bfx8*)&Sb[wid][(lt * 16 + rr) * 36 + ko];
#pragma unroll
        for (int pt = 0; pt < 4; pt++){
          bfx8 bb = *(const bfx8*)&XdTq[(pt * 16 + rr) * 72 + sub * 32 + ko];
          acc[lt][pt] = __builtin_amdgcn_mfma_f32_16x16x32_bf16(a1, bb, acc[lt][pt], 0, 0, 0);
        }
      }
    }
  }
  float Dh = Dv[h];
#pragma unroll
  for (int lt = 0; lt < 4; lt++)
#pragma unroll
    for (int pt = 0; pt < 4; pt++)
#pragma unroll
      for (int r4 = 0; r4 < 4; r4++){
        int lrow = wid * 64 + lt * 16 + (lane >> 4) * 4 + r4;
        int pcol = pt * 16 + rr;
        long gi = (rowbase + lrow) * 4096 + h * 64 + pcol;
        ybuf[gi] = f2bf(acc[lt][pt][r4] + bf2f(xact[gi]) * Dh);
      }
}

// ---------------- RMSNorm + silu(z) gate (may write in place over ybuf) ----------------
__global__ __launch_bounds__(256) void rms_kernel(const u16* ybuf, const u16* zbuf,
                                                  const float* __restrict__ norm_w, u16* ynorm){
  __shared__ float red[4];
  long row = blockIdx.x;
  int tid = threadIdx.x;
  long yb = row * 4096 + tid * 16;
  bfx8 v0 = *(const bfx8*)&ybuf[yb];
  bfx8 v1 = *(const bfx8*)&ybuf[yb + 8];
  float vals[16];
#pragma unroll
  for (int t = 0; t < 8; t++){ vals[t] = bf2f((u16)v0[t]); vals[8 + t] = bf2f((u16)v1[t]); }
  float ss = 0.f;
#pragma unroll
  for (int t = 0; t < 16; t++) ss += vals[t] * vals[t];
#pragma unroll
  for (int off = 32; off >= 1; off >>= 1) ss += __shfl_xor(ss, off);
  if ((tid & 63) == 0) red[tid >> 6] = ss;
  __syncthreads();
  float rs = rsqrtf((red[0] + red[1] + red[2] + red[3]) * (1.f / 4096.f) + 1e-5f);
  bfx8 z0 = *(const bfx8*)&zbuf[yb];
  bfx8 z1 = *(const bfx8*)&zbuf[yb + 8];
  bfx8 o0, o1;
#pragma unroll
  for (int t = 0; t < 16; t++){
    float zv = bf2f((u16)(t < 8 ? z0[t] : z1[t - 8]));
    float g = zv / (1.f + expf(-zv));
    u16 r = f2bf(vals[t] * rs * norm_w[tid * 16 + t] * g);
    if (t < 8) o0[t] = (short)r; else o1[t - 8] = (short)r;
  }
  *(bfx8*)&ynorm[yb] = o0;
  *(bfx8*)&ynorm[yb + 8] = o1;
}

extern "C" void kernel_launch(void* const* d_in, const int* in_sizes, int n_in,
                              void* d_out, int out_size, void* d_ws, size_t ws_size,
                              hipStream_t stream){
  const float* hs   = (const float*)d_in[0];
  const float* inw  = (const float*)d_in[1];
  const float* cw   = (const float*)d_in[2];
  const float* cb   = (const float*)d_in[3];
  const float* dtb  = (const float*)d_in[4];
  const float* alog = (const float*)d_in[5];
  const float* Dv   = (const float*)d_in[6];
  const float* nw   = (const float*)d_in[7];
  const float* outw = (const float*)d_in[8];

  // Workspace layout: 147,857,408 B required. z lives in d_out (exactly 64 MiB).
  const size_t REQ = 147857408ULL;
  if (ws_size < REQ){
    hipMemsetAsync(d_out, 0x42, (size_t)out_size * 4, stream);
    return;
  }
  char* ws = (char*)d_ws;
  u16*   hsb  = (u16*)  (ws + 0L);             // 33,554,432   (dead after gemm1)
  u16*   wbi  = (u16*)  (ws + 33554432L);      // 34,603,008   (dead after gemm1)
  u16*   xbc  = (u16*)  (ws + 68157440L);      // 71,303,168   (dead after conv)
  u16*   xact = (u16*)  (ws + 0L);             // 67,108,864   (overlays hsb+wbi; = ybuf = ynorm)
  u16*   stR  = (u16*)  (ws + 68157440L);      // 33,554,432   (overlays xbc)
  u16*   wbo  = (u16*)  (ws + 101711872L);     // 16,777,216   (overlays xbc)
  u16*   bmatT= (u16*)  (ws + 118489088L);     //  2,097,152   (overlays xbc tail)
  float* dtp  = (float*)(ws + 139460608L);     //  2,097,152
  float* acum = (float*)(ws + 141557760L);     //  2,097,152
  float* suma = (float*)(ws + 143654912L);     //      8,192
  u16*   bmat = (u16*)  (ws + 143663104L);     //  2,097,152
  u16*   cmat = (u16*)  (ws + 145760256L);     //  2,097,152  (end = 147,857,408)
  u16*   zbuf = (u16*)  d_out;                 // 67,108,864 = exactly out_size*4

  cvt_kernel<<<16384, 256, 0, stream>>>(hs, hsb, 4194304);
  cvt_kernel<<<16896, 256, 0, stream>>>(inw, wbi, 4325376);
  gemm_bt<0><<<dim3(64, 66), 256, 0, stream>>>(hsb, wbi, zbuf, xbc, 2048, 4096, 4352, 32);
  dt_kernel<<<256, 256, 0, stream>>>(hs, inw, dtb, dtp);
  acum_kernel<<<2048, 64, 0, stream>>>(dtp, alog, acum, suma);
  conv_kernel<<<8192, 256, 0, stream>>>(xbc, cw, cb, xact, bmat, cmat);    // xact over dead hsb+wbi
  cvt_kernel<<<8192, 256, 0, stream>>>(outw, wbo, 2097152);                // wbo over dead xbc
  bt_transpose<<<64, 256, 0, stream>>>(bmat, bmatT);
  states_kernel<<<2048, 256, 0, stream>>>(xact, bmatT, acum, suma, dtp, stR);
  scan_kernel<<<128, 256, 0, stream>>>(stR, suma);
  ydiag_kernel<<<2048, 256, 0, stream>>>(cmat, bmat, xact, stR, acum, dtp, Dv, xact);  // in-place Y
  rms_kernel<<<8192, 256, 0, stream>>>(xact, zbuf, nw, xact);                           // in-place norm
  gemm_bt<1><<<dim3(64, 16), 256, 0, stream>>>(xact, wbo, d_out, d_out, 4096, 2048, 2048, 999);
}